// Round 16
// baseline (181.887 us; speedup 1.0000x reference)
//
#include <hip/hip_runtime.h>

typedef __attribute__((ext_vector_type(8))) short short8;
typedef __attribute__((ext_vector_type(4))) float f32x4;
typedef __attribute__((ext_vector_type(4))) unsigned short us4;
typedef unsigned short u16;

#define MFMA16(a, b, c) __builtin_amdgcn_mfma_f32_16x16x32_bf16(a, b, c, 0, 0, 0)

// Q pre-scale: (1/sqrt(64)) * log2(e) — attention softmax runs in exp2 domain.
#define QSCALE 0.18033688011112042f

static __device__ __forceinline__ u16 f2bf(float f) {
  union { float f; unsigned u; } v; v.f = f;
  unsigned r = v.u + 0x7fffu + ((v.u >> 16) & 1u);
  return (u16)(r >> 16);
}

static __device__ __forceinline__ unsigned cvtpk(float lo, float hi) {
  unsigned r;
  asm("v_cvt_pk_bf16_f32 %0, %1, %2" : "=v"(r) : "v"(lo), "v"(hi));
  return r;
}

// Raw HW exp2: single v_exp_f32 (exp2f libm = multi-op OCML; __expf = mul+exp).
static __device__ __forceinline__ float fexp2(float x) {
#if __has_builtin(__builtin_amdgcn_exp2f)
  return __builtin_amdgcn_exp2f(x);
#else
  float r; asm("v_exp_f32 %0, %1" : "=v"(r) : "v"(x)); return r;
#endif
}

static __device__ __forceinline__ void gl_lds16(const u16* g, u16* l) {
  __builtin_amdgcn_global_load_lds((const __attribute__((address_space(1))) void*)g,
                                   (__attribute__((address_space(3))) void*)l,
                                   16, 0, 0);
}

#define BAR() do { __builtin_amdgcn_sched_barrier(0); \
                   __builtin_amdgcn_s_barrier();      \
                   __builtin_amdgcn_sched_barrier(0); } while (0)
#define LGK() do { asm volatile("s_waitcnt lgkmcnt(0)" ::: "memory"); \
                   __builtin_amdgcn_sched_barrier(0); } while (0)

// ---------------------------------------------------------------------------
// f32 -> bf16 convert, 8 elems/thread, grid-stride.
// ---------------------------------------------------------------------------
__global__ __launch_bounds__(256)
void cvt_bf16(const float* __restrict__ src, u16* __restrict__ dst, int n8)
{
  int i = blockIdx.x * 256 + threadIdx.x;
  const int stride = gridDim.x * 256;
  for (; i < n8; i += stride) {
    f32x4 a = ((const f32x4*)src)[2 * i];
    f32x4 b = ((const f32x4*)src)[2 * i + 1];
    short8 o;
    o[0] = (short)f2bf(a[0]); o[1] = (short)f2bf(a[1]);
    o[2] = (short)f2bf(a[2]); o[3] = (short)f2bf(a[3]);
    o[4] = (short)f2bf(b[0]); o[5] = (short)f2bf(b[1]);
    o[6] = (short)f2bf(b[2]); o[7] = (short)f2bf(b[3]);
    ((short8*)dst)[i] = o;
  }
}

// ---------------------------------------------------------------------------
// Shared QKV epilogue: scatter acc[8][4] (wave tile 128x64 of a 256x256 C
// tile) into Q [bh][t][64] (x QSCALE), K [bh][t][64], VT [bh][dh][2048].
// ---------------------------------------------------------------------------
static __device__ __forceinline__ void qkv_scatter(
    f32x4 (*acc)[4], u16* __restrict__ outp,
    long m0, long n0, int wr, int wc, int l15, int g)
{
  #pragma unroll
  for (int mi = 0; mi < 8; ++mi) {
    long m = m0 + wr * 128 + mi * 16 + g * 4;   // rows m..m+3
    int b = (int)(m >> 11);
    int t = (int)(m & 2047);
    #pragma unroll
    for (int nj = 0; nj < 4; ++nj) {
      int e = (int)n0 + wc * 64 + nj * 16 + l15;   // 0..3071
      int sel = e >> 10;                            // 0=Q 1=K 2=V
      int ee = e & 1023;
      int h = ee >> 6, dh = ee & 63;
      size_t bh131k = (size_t)(b * 16 + h) * 131072u;
      if (sel < 2) {
        float sc = (sel == 0) ? QSCALE : 1.0f;     // fold 1/sqrt(64)*log2e in Q
        size_t base = (size_t)sel * 8388608u + bh131k + (size_t)t * 64u + dh;
        #pragma unroll
        for (int r = 0; r < 4; ++r)
          outp[base + (size_t)r * 64u] = f2bf(acc[mi][nj][r] * sc);
      } else {
        size_t base = 16777216u + bh131k + (size_t)dh * 2048u + (size_t)t;
        us4 v;
        #pragma unroll
        for (int r = 0; r < 4; ++r) v[r] = f2bf(acc[mi][nj][r]);
        *(us4*)&outp[base] = v;
      }
    }
  }
}

// ---------------------------------------------------------------------------
// QKV GEMM, phased, 2 blocks/CU: 256x256 tile, BK=32, 8 waves (2M x 4N),
// 64KB dynamic LDS (2 bufs x (A 16KB + B 16KB)).
// R15 BUGFIX: each 256-row x 32-elem plane = 1024 16B chunks -> ST_A/ST_B
// must issue TWO gl_lds per thread (chunks tid and tid+512); R15 issued one,
// leaving rows 128-255 unstaged (NaN from uninitialized LDS).
//
// Per K-tile: P0 {stage A(T+1) x2 | vmcnt(2) | bar | read B + A[0-3] | lgk |
// 16 MFMA}, P1 {stage B(T+1) x2 | bar | read A[4-7] | lgk | 16 MFMA},
// trailing bar. vmcnt trace (2-load groups): prologue {A0,B0} = 4; P0 issues
// A(T+1)x2 -> 6, vmcnt(2) drains tile T's 4; P1 issues B(T+1)x2 -> 4;
// last tile vmcnt(0). Stage issues always follow the prior trailing bar.
// LDS row layout + swizzle identical to gemm8p (phys chunk = log^((r>>1)&3)).
// ---------------------------------------------------------------------------
__global__ __launch_bounds__(512, 2)
void gemm2p256(const u16* __restrict__ A, const u16* __restrict__ B,
               u16* __restrict__ outp)
{
  extern __shared__ u16 lds[];   // 65536 B = 32768 elems

  const int tid = threadIdx.x;   // 0..511
  const int lane = tid & 63;
  const int l15 = lane & 15, g = lane >> 4;
  const int w = tid >> 6;
  const int wr = w >> 2, wc = w & 3;

  // XCD-chunked decode: 384 blocks = 8 XCD x (8 m-tiles x 6 n-tiles)
  const int bid = blockIdx.x;
  const int xcd = bid & 7, idx = bid >> 3;
  const int cx = xcd & 3, cy = xcd >> 2;
  const int mt = cx * 8 + (idx & 7);      // 0..31
  const int nt = cy * 6 + (idx >> 3);     // 0..11
  const long m0 = (long)mt * 256;
  const long n0 = (long)nt * 256;

  f32x4 acc[8][4] = {};

  // staging: 1024 chunks per plane, 2 loads/thread (c0 = tid, c1 = tid+512)
  const int c0 = tid, c1 = tid + 512;
  const int ar0 = c0 >> 2, ap0 = (c0 & 3) ^ ((ar0 >> 1) & 3);
  const int ar1 = c1 >> 2, ap1 = (c1 & 3) ^ ((ar1 >> 1) & 3);
  const u16* sA0 = A + (m0 + ar0) * 1024 + ap0 * 8;
  const u16* sA1 = A + (m0 + ar1) * 1024 + ap1 * 8;
  const u16* sB0 = B + (n0 + ar0) * 1024 + ap0 * 8;
  const u16* sB1 = B + (n0 + ar1) * 1024 + ap1 * 8;

  // frag offsets (elems) within a buffer. buf: A @0, B @8192; stride 16384.
  int aoff[8], boff[4];
  #pragma unroll
  for (int mi = 0; mi < 8; ++mi) {
    int r = wr * 128 + mi * 16 + l15;
    aoff[mi] = r * 32 + (g ^ ((r >> 1) & 3)) * 8;
  }
  #pragma unroll
  for (int nj = 0; nj < 4; ++nj) {
    int r = wc * 64 + nj * 16 + l15;
    boff[nj] = 8192 + r * 32 + (g ^ ((r >> 1) & 3)) * 8;
  }

#define ST_A(kt, b) do { \
    gl_lds16(sA0 + (kt) * 32, &lds[(b) * 16384 + c0 * 8]); \
    gl_lds16(sA1 + (kt) * 32, &lds[(b) * 16384 + c1 * 8]); \
  } while (0)
#define ST_B(kt, b) do { \
    gl_lds16(sB0 + (kt) * 32, &lds[(b) * 16384 + 8192 + c0 * 8]); \
    gl_lds16(sB1 + (kt) * 32, &lds[(b) * 16384 + 8192 + c1 * 8]); \
  } while (0)

  ST_A(0, 0); ST_B(0, 0);   // prologue: tile 0 (4 loads)

  for (int kt = 0; kt < 32; ++kt) {
    const int b = kt & 1, nb = b ^ 1;
    const bool more = (kt < 31);
    const u16* L = lds + b * 16384;
    short8 bf[4], af[4];

    // ---- P0: stage A(T+1) | vmcnt(2) | bar | read B + A[0-3] | 16 MFMA ----
    if (more) { ST_A(kt + 1, nb);
                asm volatile("s_waitcnt vmcnt(2)" ::: "memory"); }
    else      { asm volatile("s_waitcnt vmcnt(0)" ::: "memory"); }
    BAR();
    #pragma unroll
    for (int nj = 0; nj < 4; ++nj) bf[nj] = *(const short8*)&L[boff[nj]];
    #pragma unroll
    for (int mi = 0; mi < 4; ++mi) af[mi] = *(const short8*)&L[aoff[mi]];
    LGK();
    __builtin_amdgcn_s_setprio(1);
    #pragma unroll
    for (int mi = 0; mi < 4; ++mi)
      #pragma unroll
      for (int nj = 0; nj < 4; ++nj)
        acc[mi][nj] = MFMA16(af[mi], bf[nj], acc[mi][nj]);
    __builtin_amdgcn_s_setprio(0);

    // ---- P1: stage B(T+1) | bar | read A[4-7] | 16 MFMA ----
    if (more) ST_B(kt + 1, nb);
    BAR();
    #pragma unroll
    for (int mi = 0; mi < 4; ++mi) af[mi] = *(const short8*)&L[aoff[mi + 4]];
    LGK();
    __builtin_amdgcn_s_setprio(1);
    #pragma unroll
    for (int mi = 0; mi < 4; ++mi)
      #pragma unroll
      for (int nj = 0; nj < 4; ++nj)
        acc[mi + 4][nj] = MFMA16(af[mi], bf[nj], acc[mi + 4][nj]);
    __builtin_amdgcn_s_setprio(0);

    BAR();   // trailing: all reads of buf[b] done -> T+1 may overwrite it
  }
#undef ST_A
#undef ST_B

  qkv_scatter(acc, outp, m0, n0, wr, wc, l15, g);
}

// ---------------------------------------------------------------------------
// Fallback QKV GEMM (proven 128^2 structure) — used only if the
// dynamic-LDS attribute call fails.
// ---------------------------------------------------------------------------
__global__ __launch_bounds__(256)
void gemm_qkv_fb(const u16* __restrict__ A, const u16* __restrict__ B,
                 u16* __restrict__ outp)
{
  __shared__ u16 Ash[128 * 32];
  __shared__ u16 Bsh[128 * 32];
  const int tid = threadIdx.x;
  const int lane = tid & 63;
  const int l15 = lane & 15, g = lane >> 4;
  const int w = tid >> 6;
  const int wr = w >> 1, wc = w & 1;

  const int bid = blockIdx.x;
  const int xcd = bid & 7, idx = bid >> 3;
  const int cx = xcd & 3, cy = xcd >> 2;
  const int mt = cx * 16 + (idx & 15);
  const int nt = cy * 12 + (idx >> 4);
  const long m0 = (long)mt * 128;
  const long n0 = (long)nt * 128;

  f32x4 acc[4][4] = {};

  const int c0 = tid, c1 = tid + 256;
  const u16* pa0 = A + (m0 + (c0 >> 2)) * 1024 + (c0 & 3) * 8;
  const u16* pa1 = A + (m0 + (c1 >> 2)) * 1024 + (c1 & 3) * 8;
  const u16* pb0 = B + (n0 + (c0 >> 2)) * 1024 + (c0 & 3) * 8;
  const u16* pb1 = B + (n0 + (c1 >> 2)) * 1024 + (c1 & 3) * 8;
  u16* la0 = Ash + c0 * 8;
  u16* la1 = Ash + c1 * 8;
  u16* lb0 = Bsh + c0 * 8;
  u16* lb1 = Bsh + c1 * 8;

  const u16* afp[4];
  const u16* bfp[4];
  #pragma unroll
  for (int mi = 0; mi < 4; ++mi)
    afp[mi] = &Ash[(wr * 64 + mi * 16 + l15) * 32 + g * 8];
  #pragma unroll
  for (int ni = 0; ni < 4; ++ni)
    bfp[ni] = &Bsh[(wc * 64 + ni * 16 + l15) * 32 + g * 8];

  for (int k0 = 0; k0 < 1024; k0 += 32) {
    __syncthreads();
    gl_lds16(pa0, la0); gl_lds16(pa1, la1);
    gl_lds16(pb0, lb0); gl_lds16(pb1, lb1);
    pa0 += 32; pa1 += 32; pb0 += 32; pb1 += 32;
    __syncthreads();
    short8 af[4], bf[4];
    #pragma unroll
    for (int mi = 0; mi < 4; ++mi) af[mi] = *(const short8*)afp[mi];
    #pragma unroll
    for (int ni = 0; ni < 4; ++ni) bf[ni] = *(const short8*)bfp[ni];
    #pragma unroll
    for (int mi = 0; mi < 4; ++mi)
      #pragma unroll
      for (int ni = 0; ni < 4; ++ni)
        acc[mi][ni] = MFMA16(af[mi], bf[ni], acc[mi][ni]);
  }

  #pragma unroll
  for (int mi = 0; mi < 4; ++mi) {
    long m = m0 + wr * 64 + mi * 16 + g * 4;
    int b = (int)(m >> 11);
    int t = (int)(m & 2047);
    #pragma unroll
    for (int ni = 0; ni < 4; ++ni) {
      int e = (int)n0 + wc * 64 + ni * 16 + l15;
      int sel = e >> 10;
      int ee = e & 1023;
      int h = ee >> 6, dh = ee & 63;
      size_t bh131k = (size_t)(b * 16 + h) * 131072u;
      if (sel < 2) {
        float sc = (sel == 0) ? QSCALE : 1.0f;
        size_t base = (size_t)sel * 8388608u + bh131k + (size_t)t * 64u + dh;
        #pragma unroll
        for (int r = 0; r < 4; ++r)
          outp[base + (size_t)r * 64u] = f2bf(acc[mi][ni][r] * sc);
      } else {
        size_t base = 16777216u + bh131k + (size_t)dh * 2048u + (size_t)t;
        us4 v;
        #pragma unroll
        for (int r = 0; r < 4; ++r) v[r] = f2bf(acc[mi][ni][r]);
        *(us4*)&outp[base] = v;
      }
    }
  }
}

// ---------------------------------------------------------------------------
// Output GEMM (128^2 structure): C = A_headed * w_out^T, f32 store.
// (VERBATIM — passed.)
// ---------------------------------------------------------------------------
__global__ __launch_bounds__(256)
void gemm_out(const u16* __restrict__ A, const u16* __restrict__ B,
              float* __restrict__ outf)
{
  __shared__ u16 Ash[128 * 32];
  __shared__ u16 Bsh[128 * 32];
  const int tid = threadIdx.x;
  const int lane = tid & 63;
  const int l15 = lane & 15, g = lane >> 4;
  const int w = tid >> 6;
  const int wr = w >> 1, wc = w & 1;

  const int bid = blockIdx.x;
  const int xcd = bid & 7, idx = bid >> 3;
  const int cx = xcd & 3, cy = xcd >> 2;
  const int mt = cx * 16 + (idx & 15);
  const int nt = cy * 4 + (idx >> 4);
  const long m0 = (long)mt * 128;
  const long n0 = (long)nt * 128;

  f32x4 acc[4][4] = {};

  const int c0 = tid, c1 = tid + 256;
  const long arow0 = m0 + (c0 >> 2), arow1 = m0 + (c1 >> 2);
  int b0 = (int)(arow0 >> 11), t0 = (int)(arow0 & 2047);
  int b1 = (int)(arow1 >> 11), t1 = (int)(arow1 & 2047);
  const u16* pa0 = A + (size_t)(b0 * 16) * 131072u + (size_t)t0 * 64u + (c0 & 3) * 8;
  const u16* pa1 = A + (size_t)(b1 * 16) * 131072u + (size_t)t1 * 64u + (c1 & 3) * 8;
  const u16* pb0 = B + (n0 + (c0 >> 2)) * 1024 + (c0 & 3) * 8;
  const u16* pb1 = B + (n0 + (c1 >> 2)) * 1024 + (c1 & 3) * 8;
  u16* la0 = Ash + c0 * 8;
  u16* la1 = Ash + c1 * 8;
  u16* lb0 = Bsh + c0 * 8;
  u16* lb1 = Bsh + c1 * 8;

  const u16* afp[4];
  const u16* bfp[4];
  #pragma unroll
  for (int mi = 0; mi < 4; ++mi)
    afp[mi] = &Ash[(wr * 64 + mi * 16 + l15) * 32 + g * 8];
  #pragma unroll
  for (int ni = 0; ni < 4; ++ni)
    bfp[ni] = &Bsh[(wc * 64 + ni * 16 + l15) * 32 + g * 8];

  for (int k0 = 0; k0 < 1024; k0 += 32) {
    __syncthreads();
    gl_lds16(pa0, la0); gl_lds16(pa1, la1);
    gl_lds16(pb0, lb0); gl_lds16(pb1, lb1);
    long d = (k0 & 32) ? (131072 - 32) : 32;
    pa0 += d; pa1 += d;
    pb0 += 32; pb1 += 32;
    __syncthreads();

    short8 af[4], bf[4];
    #pragma unroll
    for (int mi = 0; mi < 4; ++mi) af[mi] = *(const short8*)afp[mi];
    #pragma unroll
    for (int ni = 0; ni < 4; ++ni) bf[ni] = *(const short8*)bfp[ni];
    #pragma unroll
    for (int mi = 0; mi < 4; ++mi)
      #pragma unroll
      for (int ni = 0; ni < 4; ++ni)
        acc[mi][ni] = MFMA16(af[mi], bf[ni], acc[mi][ni]);
  }

  #pragma unroll
  for (int mi = 0; mi < 4; ++mi) {
    long m = m0 + wr * 64 + mi * 16 + g * 4;
    #pragma unroll
    for (int ni = 0; ni < 4; ++ni) {
      int n = (int)n0 + wc * 64 + ni * 16 + l15;
      #pragma unroll
      for (int r = 0; r < 4; ++r)
        outf[(m + r) * 1024 + n] = acc[mi][ni][r];
    }
  }
}

// ---------------------------------------------------------------------------
// Causal flash attention, swapped-QK^T form, SINGLE-SEGMENT.
// (VERBATIM from R14 — passed at 73.2us.)
// ---------------------------------------------------------------------------
__global__ __launch_bounds__(512, 4)
void attn(const u16* __restrict__ Q, const u16* __restrict__ K,
          const u16* __restrict__ VT, u16* __restrict__ O)
{
  __shared__ u16 Ksh[2][64 * 64];
  __shared__ u16 Vsh[2][64 * 64];
  __shared__ u16 Psh[8][16 * 64];

  const int tid = threadIdx.x;
  const int lane = tid & 63;
  const int l15 = lane & 15, g = lane >> 4;
  const int w = tid >> 6;
  const int bid = blockIdx.x;
  const int qi = (bid < 256) ? (7 - (bid >> 6)) : ((bid - 256) >> 6);
  const int bh = bid & 63;
  const int q0 = qi * 256;
  const int qb = q0 + w * 32;
  const int nt = qi * 4 + 4;

  const u16* Qp = Q + (size_t)bh * 131072u;
  const u16* Kp = K + (size_t)bh * 131072u;
  const u16* Vp = VT + (size_t)bh * 131072u;

  short8 qf[2][2];
  #pragma unroll
  for (int mi = 0; mi < 2; ++mi)
    #pragma unroll
    for (int kc = 0; kc < 2; ++kc)
      qf[mi][kc] = *(const short8*)&Qp[(qb + mi * 16 + l15) * 64 + kc * 32 + g * 8];

  f32x4 oacc[2][4] = {};
  float mrun[2] = {-1e30f, -1e30f};
  float lrun[2] = {0.f, 0.f};

  const int rA = tid >> 3, uA = ((tid & 7) ^ (rA & 7)) * 8;

#define STAGE(kv0s, b) do {                                            \
    gl_lds16(Kp + ((kv0s) + rA) * 64 + uA, Ksh[b] + tid * 8);          \
    gl_lds16(Vp + (size_t)rA * 2048u + (kv0s) + uA, Vsh[b] + tid * 8); \
  } while (0)

  STAGE(0, 0);
  int cur = 0;

  for (int ti = 0; ti < nt; ++ti) {
    const int kv0 = ti * 64;
    if (ti + 1 < nt) {
      STAGE(kv0 + 64, cur ^ 1);
      asm volatile("s_waitcnt vmcnt(2)" ::: "memory");
    } else {
      asm volatile("s_waitcnt vmcnt(0)" ::: "memory");
    }
    __builtin_amdgcn_s_barrier();
    __builtin_amdgcn_sched_barrier(0);

    if (kv0 <= qb + 31) {
      const u16* Kb = Ksh[cur];
      const u16* Vb = Vsh[cur];

      f32x4 s[2][4] = {};
      #pragma unroll
      for (int kc = 0; kc < 2; ++kc)
        #pragma unroll
        for (int ni = 0; ni < 4; ++ni) {
          int row = ni * 16 + l15;
          short8 kb = *(const short8*)&Kb[row * 64 + (((kc * 4 + g) ^ (row & 7)) << 3)];
          #pragma unroll
          for (int mi = 0; mi < 2; ++mi)
            s[mi][ni] = MFMA16(kb, qf[mi][kc], s[mi][ni]);
        }

      if (kv0 + 63 > qb) {
        #pragma unroll
        for (int mi = 0; mi < 2; ++mi) {
          int qv = qb + mi * 16 + l15;
          #pragma unroll
          for (int ni = 0; ni < 4; ++ni)
            #pragma unroll
            for (int r = 0; r < 4; ++r)
              if (kv0 + ni * 16 + g * 4 + r > qv)
                s[mi][ni][r] = -1e30f;
        }
      }

      #pragma unroll
      for (int mi = 0; mi < 2; ++mi) {
        // 16-value row max as max3 triples (5 max3 + 2 max3 + 1 max)
        float t0 = fmaxf(fmaxf(s[mi][0][0], s[mi][0][1]), s[mi][0][2]);
        float t1 = fmaxf(fmaxf(s[mi][0][3], s[mi][1][0]), s[mi][1][1]);
        float t2 = fmaxf(fmaxf(s[mi][1][2], s[mi][1][3]), s[mi][2][0]);
        float t3 = fmaxf(fmaxf(s[mi][2][1], s[mi][2][2]), s[mi][2][3]);
        float t4 = fmaxf(fmaxf(s[mi][3][0], s[mi][3][1]), s[mi][3][2]);
        float mx = fmaxf(fmaxf(fmaxf(t0, t1), t2),
                         fmaxf(fmaxf(t3, t4), s[mi][3][3]));
        mx = fmaxf(mx, __shfl_xor(mx, 16));
        mx = fmaxf(mx, __shfl_xor(mx, 32));
        if (!__all(mx - mrun[mi] <= 11.0f)) {      // exp2-domain defer-max
          float mn = fmaxf(mrun[mi], mx);
          float sc = fexp2(mrun[mi] - mn);
          mrun[mi] = mn;
          lrun[mi] *= sc;
          #pragma unroll
          for (int nj = 0; nj < 4; ++nj) {
            oacc[mi][nj][0] *= sc;
            oacc[mi][nj][1] *= sc;
            oacc[mi][nj][2] *= sc;
            oacc[mi][nj][3] *= sc;
          }
        }
        float mn = mrun[mi];
        float rs = 0.f;
        #pragma unroll
        for (int ni = 0; ni < 4; ++ni)
          #pragma unroll
          for (int r = 0; r < 4; ++r) {
            float pe = fexp2(s[mi][ni][r] - mn);   // bare v_exp_f32
            s[mi][ni][r] = pe;
            rs += pe;
          }
        rs += __shfl_xor(rs, 16);
        rs += __shfl_xor(rs, 32);
        lrun[mi] += rs;
      }

      u16* Pw = &Psh[w][0];
      short8 pb[2][2];
      #pragma unroll
      for (int mi = 0; mi < 2; ++mi) {
        #pragma unroll
        for (int ni = 0; ni < 4; ++ni) {
          int col = ni * 16 + g * 4;
          uint2 pv;
          pv.x = cvtpk(s[mi][ni][0], s[mi][ni][1]);
          pv.y = cvtpk(s[mi][ni][2], s[mi][ni][3]);
          *(uint2*)&Pw[l15 * 64 + (col ^ ((l15 & 7) << 3))] = pv;
        }
        #pragma unroll
        for (int kc = 0; kc < 2; ++kc)
          pb[mi][kc] = *(const short8*)&Pw[l15 * 64 + (((kc * 4 + g) ^ (l15 & 7)) << 3)];
      }

      #pragma unroll
      for (int kc = 0; kc < 2; ++kc)
        #pragma unroll
        for (int nj = 0; nj < 4; ++nj) {
          int vrow = nj * 16 + l15;
          short8 vb = *(const short8*)&Vb[vrow * 64 + (((kc * 4 + g) ^ (vrow & 7)) << 3)];
          #pragma unroll
          for (int mi = 0; mi < 2; ++mi)
            oacc[mi][nj] = MFMA16(vb, pb[mi][kc], oacc[mi][nj]);
        }
    }

    __builtin_amdgcn_sched_barrier(0);
    __builtin_amdgcn_s_barrier();
    cur ^= 1;
  }
#undef STAGE

  #pragma unroll
  for (int mi = 0; mi < 2; ++mi) {
    float inv = 1.0f / lrun[mi];
    int t = qb + mi * 16 + l15;
    size_t base = (size_t)bh * 131072u + (size_t)t * 64u;
    #pragma unroll
    for (int nj = 0; nj < 4; ++nj) {
      uint2 o;
      o.x = cvtpk(oacc[mi][nj][0] * inv, oacc[mi][nj][1] * inv);
      o.y = cvtpk(oacc[mi][nj][2] * inv, oacc[mi][nj][3] * inv);
      *(uint2*)&O[base + nj * 16 + g * 4] = o;
    }
  }
}

// ---------------------------------------------------------------------------
extern "C" void kernel_launch(void* const* d_in, const int* in_sizes, int n_in,
                              void* d_out, int out_size, void* d_ws, size_t ws_size,
                              hipStream_t stream)
{
  (void)in_sizes; (void)n_in; (void)out_size; (void)ws_size;
  const float* x    = (const float*)d_in[0];   // [8192][1024] f32
  const float* wqkv = (const float*)d_in[1];   // [3072][1024] f32
  const float* wout = (const float*)d_in[2];   // [1024][1024] f32
  u16* ws  = (u16*)d_ws;
  u16* Qw   = ws;                  // Q [bh][t][64]; later attn O (same layout)
  u16* Kw   = ws + 8388608;        // K [bh][t][64]
  u16* VTw  = ws + 16777216;       // VT [bh][dh][2048]
  u16* wqb  = ws + 25165824;       // w_qkv bf16 [3072][1024]
  u16* wob  = ws + 28311552;       // w_out bf16 [1024][1024]
  u16* xb   = (u16*)d_out;         // x bf16 [8192][1024] staged in d_out
  float* y  = (float*)d_out;       // final f32 output (overwrites xb)

  hipLaunchKernelGGL(cvt_bf16, dim3(2048), dim3(256), 0, stream, x,    xb,  1048576);
  hipLaunchKernelGGL(cvt_bf16, dim3(1536), dim3(256), 0, stream, wqkv, wqb, 393216);
  hipLaunchKernelGGL(cvt_bf16, dim3(512),  dim3(256), 0, stream, wout, wob, 131072);

  // 64KB dynamic LDS opt-in (idempotent host-side call); legacy fallback.
  hipError_t e = hipFuncSetAttribute((const void*)gemm2p256,
                   hipFuncAttributeMaxDynamicSharedMemorySize, 65536);
  if (e == hipSuccess) {
    hipLaunchKernelGGL(gemm2p256, dim3(384), dim3(512), 65536, stream, xb, wqb, ws);
  } else {
    hipLaunchKernelGGL(gemm_qkv_fb, dim3(1536), dim3(256), 0, stream, xb, wqb, ws);
  }

  hipLaunchKernelGGL(attn,     dim3(512), dim3(512), 0, stream, Qw, Kw, VTw, Qw);
  hipLaunchKernelGGL(gemm_out, dim3(512), dim3(256), 0, stream, Qw, wob, y);
}

// Round 17
// 178.549 us; speedup vs baseline: 1.0187x; 1.0187x over previous
//
#include <hip/hip_runtime.h>

typedef __attribute__((ext_vector_type(8))) short short8;
typedef __attribute__((ext_vector_type(4))) float f32x4;
typedef __attribute__((ext_vector_type(4))) unsigned short us4;
typedef unsigned short u16;

#define MFMA16(a, b, c) __builtin_amdgcn_mfma_f32_16x16x32_bf16(a, b, c, 0, 0, 0)

// Q pre-scale: (1/sqrt(64)) * log2(e) — attention softmax runs in exp2 domain.
#define QSCALE 0.18033688011112042f

static __device__ __forceinline__ u16 f2bf(float f) {
  union { float f; unsigned u; } v; v.f = f;
  unsigned r = v.u + 0x7fffu + ((v.u >> 16) & 1u);
  return (u16)(r >> 16);
}

static __device__ __forceinline__ unsigned cvtpk(float lo, float hi) {
  unsigned r;
  asm("v_cvt_pk_bf16_f32 %0, %1, %2" : "=v"(r) : "v"(lo), "v"(hi));
  return r;
}

// Raw HW exp2: single v_exp_f32 (exp2f libm = multi-op OCML; __expf = mul+exp).
static __device__ __forceinline__ float fexp2(float x) {
#if __has_builtin(__builtin_amdgcn_exp2f)
  return __builtin_amdgcn_exp2f(x);
#else
  float r; asm("v_exp_f32 %0, %1" : "=v"(r) : "v"(x)); return r;
#endif
}

static __device__ __forceinline__ void gl_lds16(const u16* g, u16* l) {
  __builtin_amdgcn_global_load_lds((const __attribute__((address_space(1))) void*)g,
                                   (__attribute__((address_space(3))) void*)l,
                                   16, 0, 0);
}

#define BAR() do { __builtin_amdgcn_sched_barrier(0); \
                   __builtin_amdgcn_s_barrier();      \
                   __builtin_amdgcn_sched_barrier(0); } while (0)
#define LGK() do { asm volatile("s_waitcnt lgkmcnt(0)" ::: "memory"); \
                   __builtin_amdgcn_sched_barrier(0); } while (0)

// ---------------------------------------------------------------------------
// f32 -> bf16 convert, 8 elems/thread, grid-stride.
// ---------------------------------------------------------------------------
__global__ __launch_bounds__(256)
void cvt_bf16(const float* __restrict__ src, u16* __restrict__ dst, int n8)
{
  int i = blockIdx.x * 256 + threadIdx.x;
  const int stride = gridDim.x * 256;
  for (; i < n8; i += stride) {
    f32x4 a = ((const f32x4*)src)[2 * i];
    f32x4 b = ((const f32x4*)src)[2 * i + 1];
    short8 o;
    o[0] = (short)f2bf(a[0]); o[1] = (short)f2bf(a[1]);
    o[2] = (short)f2bf(a[2]); o[3] = (short)f2bf(a[3]);
    o[4] = (short)f2bf(b[0]); o[5] = (short)f2bf(b[1]);
    o[6] = (short)f2bf(b[2]); o[7] = (short)f2bf(b[3]);
    ((short8*)dst)[i] = o;
  }
}

// ---------------------------------------------------------------------------
// Shared QKV epilogue: scatter acc[8][4] (wave tile 128x64 of a 256x256 C
// tile) into Q [bh][t][64] (x QSCALE), K [bh][t][64], VT [bh][dh][2048].
// ---------------------------------------------------------------------------
static __device__ __forceinline__ void qkv_scatter(
    f32x4 (*acc)[4], u16* __restrict__ outp,
    long m0, long n0, int wr, int wc, int l15, int g)
{
  #pragma unroll
  for (int mi = 0; mi < 8; ++mi) {
    long m = m0 + wr * 128 + mi * 16 + g * 4;   // rows m..m+3
    int b = (int)(m >> 11);
    int t = (int)(m & 2047);
    #pragma unroll
    for (int nj = 0; nj < 4; ++nj) {
      int e = (int)n0 + wc * 64 + nj * 16 + l15;   // 0..3071
      int sel = e >> 10;                            // 0=Q 1=K 2=V
      int ee = e & 1023;
      int h = ee >> 6, dh = ee & 63;
      size_t bh131k = (size_t)(b * 16 + h) * 131072u;
      if (sel < 2) {
        float sc = (sel == 0) ? QSCALE : 1.0f;     // fold 1/sqrt(64)*log2e in Q
        size_t base = (size_t)sel * 8388608u + bh131k + (size_t)t * 64u + dh;
        #pragma unroll
        for (int r = 0; r < 4; ++r)
          outp[base + (size_t)r * 64u] = f2bf(acc[mi][nj][r] * sc);
      } else {
        size_t base = 16777216u + bh131k + (size_t)dh * 2048u + (size_t)t;
        us4 v;
        #pragma unroll
        for (int r = 0; r < 4; ++r) v[r] = f2bf(acc[mi][nj][r]);
        *(us4*)&outp[base] = v;
      }
    }
  }
}

// ---------------------------------------------------------------------------
// QKV GEMM, m201-style 8-phase: 256x256 tile, BK=64, 8 waves (2M x 4N),
// 128KB dynamic LDS (2 bufs x (A 32KB + B 32KB)), 1 block/CU.
// (VERBATIM from R14 — session-best gemm1 at ~65us.)
// ---------------------------------------------------------------------------
__global__ __launch_bounds__(512, 2)
void gemm8p_qkv(const u16* __restrict__ A, const u16* __restrict__ B,
                u16* __restrict__ outp)
{
  extern __shared__ u16 lds[];   // 131072 B = 65536 elems

  const int tid = threadIdx.x;   // 0..511
  const int lane = tid & 63;
  const int l15 = lane & 15, g = lane >> 4;
  const int w = tid >> 6;
  const int wr = w >> 2, wc = w & 3;

  // XCD-chunked decode: 384 blocks = 8 XCD x (8 m-tiles x 6 n-tiles)
  const int bid = blockIdx.x;
  const int xcd = bid & 7, idx = bid >> 3;
  const int cx = xcd & 3, cy = xcd >> 2;
  const int mt = cx * 8 + (idx & 7);      // 0..31
  const int nt = cy * 6 + (idx >> 3);     // 0..11
  const long m0 = (long)mt * 256;
  const long n0 = (long)nt * 256;

  f32x4 acc[8][4] = {};

  // staging chunks: c0 = tid, c1 = tid+512 within each 1024-chunk plane
  const int c0 = tid, c1 = tid + 512;
  const int ar0 = c0 >> 2, ap0 = (c0 & 3) ^ ((ar0 >> 1) & 3);
  const int ar1 = c1 >> 2, ap1 = (c1 & 3) ^ ((ar1 >> 1) & 3);
  const u16* sA0 = A + (m0 + ar0) * 1024 + ap0 * 8;
  const u16* sA1 = A + (m0 + ar1) * 1024 + ap1 * 8;
  const u16* sB0 = B + (n0 + ar0) * 1024 + ap0 * 8;
  const u16* sB1 = B + (n0 + ar1) * 1024 + ap1 * 8;

  // frag offsets (elems) within a buffer, kk=0; kk=1 adds 8192.
  // buf layout: A kh0 @0, A kh1 @8192, B kh0 @16384, B kh1 @24576.
  int aoff[8], boff[4];
  #pragma unroll
  for (int mi = 0; mi < 8; ++mi) {
    int r = wr * 128 + mi * 16 + l15;
    aoff[mi] = r * 32 + (g ^ ((r >> 1) & 3)) * 8;
  }
  #pragma unroll
  for (int nj = 0; nj < 4; ++nj) {
    int r = wc * 64 + nj * 16 + l15;
    boff[nj] = 16384 + r * 32 + (g ^ ((r >> 1) & 3)) * 8;
  }

#define ST_A(kt, b, kh) do { \
    gl_lds16(sA0 + (kt) * 64 + (kh) * 32, &lds[(b) * 32768 + (kh) * 8192 + c0 * 8]); \
    gl_lds16(sA1 + (kt) * 64 + (kh) * 32, &lds[(b) * 32768 + (kh) * 8192 + c1 * 8]); \
  } while (0)
#define ST_B(kt, b, kh) do { \
    gl_lds16(sB0 + (kt) * 64 + (kh) * 32, &lds[(b) * 32768 + 16384 + (kh) * 8192 + c0 * 8]); \
    gl_lds16(sB1 + (kt) * 64 + (kh) * 32, &lds[(b) * 32768 + 16384 + (kh) * 8192 + c1 * 8]); \
  } while (0)

  // prologue: full tile 0, order A-Kh0, B-Kh0, A-Kh1, B-Kh1 (8 loads)
  ST_A(0, 0, 0); ST_B(0, 0, 0); ST_A(0, 0, 1); ST_B(0, 0, 1);

  for (int kt = 0; kt < 16; ++kt) {
    const int b = kt & 1, nb = b ^ 1;
    const bool more = (kt < 15);
    const u16* L = lds + b * 32768;
    short8 bf[4], af[4];

    // ---- P0: stage A-Kh0(T+1) | vmcnt | bar | read B.kk0 + A[0-3].kk0 ----
    if (more) { ST_A(kt + 1, nb, 0);
                asm volatile("s_waitcnt vmcnt(6)" ::: "memory"); }
    else      { asm volatile("s_waitcnt vmcnt(4)" ::: "memory"); }
    BAR();
    #pragma unroll
    for (int nj = 0; nj < 4; ++nj) bf[nj] = *(const short8*)&L[boff[nj]];
    #pragma unroll
    for (int mi = 0; mi < 4; ++mi) af[mi] = *(const short8*)&L[aoff[mi]];
    LGK();
    __builtin_amdgcn_s_setprio(1);
    #pragma unroll
    for (int mi = 0; mi < 4; ++mi)
      #pragma unroll
      for (int nj = 0; nj < 4; ++nj)
        acc[mi][nj] = MFMA16(af[mi], bf[nj], acc[mi][nj]);
    __builtin_amdgcn_s_setprio(0);

    // ---- P1: stage B-Kh0(T+1) | bar | read A[4-7].kk0 ----
    if (more) ST_B(kt + 1, nb, 0);
    BAR();
    #pragma unroll
    for (int mi = 0; mi < 4; ++mi) af[mi] = *(const short8*)&L[aoff[mi + 4]];
    LGK();
    __builtin_amdgcn_s_setprio(1);
    #pragma unroll
    for (int mi = 0; mi < 4; ++mi)
      #pragma unroll
      for (int nj = 0; nj < 4; ++nj)
        acc[mi + 4][nj] = MFMA16(af[mi], bf[nj], acc[mi + 4][nj]);
    __builtin_amdgcn_s_setprio(0);

    // ---- P2: stage A-Kh1(T+1) | vmcnt | bar | read B.kk1 + A[0-3].kk1 ----
    if (more) { ST_A(kt + 1, nb, 1);
                asm volatile("s_waitcnt vmcnt(6)" ::: "memory"); }
    else      { asm volatile("s_waitcnt vmcnt(0)" ::: "memory"); }
    BAR();
    #pragma unroll
    for (int nj = 0; nj < 4; ++nj) bf[nj] = *(const short8*)&L[boff[nj] + 8192];
    #pragma unroll
    for (int mi = 0; mi < 4; ++mi) af[mi] = *(const short8*)&L[aoff[mi] + 8192];
    LGK();
    __builtin_amdgcn_s_setprio(1);
    #pragma unroll
    for (int mi = 0; mi < 4; ++mi)
      #pragma unroll
      for (int nj = 0; nj < 4; ++nj)
        acc[mi][nj] = MFMA16(af[mi], bf[nj], acc[mi][nj]);
    __builtin_amdgcn_s_setprio(0);

    // ---- P3: stage B-Kh1(T+1) | bar | read A[4-7].kk1 ----
    if (more) ST_B(kt + 1, nb, 1);
    BAR();
    #pragma unroll
    for (int mi = 0; mi < 4; ++mi) af[mi] = *(const short8*)&L[aoff[mi + 4] + 8192];
    LGK();
    __builtin_amdgcn_s_setprio(1);
    #pragma unroll
    for (int mi = 0; mi < 4; ++mi)
      #pragma unroll
      for (int nj = 0; nj < 4; ++nj)
        acc[mi + 4][nj] = MFMA16(af[mi], bf[nj], acc[mi + 4][nj]);
    __builtin_amdgcn_s_setprio(0);

    BAR();   // trailing: all reads of buf[b] done -> T+1 may overwrite it
  }
#undef ST_A
#undef ST_B

  qkv_scatter(acc, outp, m0, n0, wr, wc, l15, g);
}

// ---------------------------------------------------------------------------
// Fallback QKV GEMM (proven 128^2 structure) — used only if the
// dynamic-LDS attribute call fails.
// ---------------------------------------------------------------------------
__global__ __launch_bounds__(256)
void gemm_qkv_fb(const u16* __restrict__ A, const u16* __restrict__ B,
                 u16* __restrict__ outp)
{
  __shared__ u16 Ash[128 * 32];
  __shared__ u16 Bsh[128 * 32];
  const int tid = threadIdx.x;
  const int lane = tid & 63;
  const int l15 = lane & 15, g = lane >> 4;
  const int w = tid >> 6;
  const int wr = w >> 1, wc = w & 1;

  const int bid = blockIdx.x;
  const int xcd = bid & 7, idx = bid >> 3;
  const int cx = xcd & 3, cy = xcd >> 2;
  const int mt = cx * 16 + (idx & 15);
  const int nt = cy * 12 + (idx >> 4);
  const long m0 = (long)mt * 128;
  const long n0 = (long)nt * 128;

  f32x4 acc[4][4] = {};

  const int c0 = tid, c1 = tid + 256;
  const u16* pa0 = A + (m0 + (c0 >> 2)) * 1024 + (c0 & 3) * 8;
  const u16* pa1 = A + (m0 + (c1 >> 2)) * 1024 + (c1 & 3) * 8;
  const u16* pb0 = B + (n0 + (c0 >> 2)) * 1024 + (c0 & 3) * 8;
  const u16* pb1 = B + (n0 + (c1 >> 2)) * 1024 + (c1 & 3) * 8;
  u16* la0 = Ash + c0 * 8;
  u16* la1 = Ash + c1 * 8;
  u16* lb0 = Bsh + c0 * 8;
  u16* lb1 = Bsh + c1 * 8;

  const u16* afp[4];
  const u16* bfp[4];
  #pragma unroll
  for (int mi = 0; mi < 4; ++mi)
    afp[mi] = &Ash[(wr * 64 + mi * 16 + l15) * 32 + g * 8];
  #pragma unroll
  for (int ni = 0; ni < 4; ++ni)
    bfp[ni] = &Bsh[(wc * 64 + ni * 16 + l15) * 32 + g * 8];

  for (int k0 = 0; k0 < 1024; k0 += 32) {
    __syncthreads();
    gl_lds16(pa0, la0); gl_lds16(pa1, la1);
    gl_lds16(pb0, lb0); gl_lds16(pb1, lb1);
    pa0 += 32; pa1 += 32; pb0 += 32; pb1 += 32;
    __syncthreads();
    short8 af[4], bf[4];
    #pragma unroll
    for (int mi = 0; mi < 4; ++mi) af[mi] = *(const short8*)afp[mi];
    #pragma unroll
    for (int ni = 0; ni < 4; ++ni) bf[ni] = *(const short8*)bfp[ni];
    #pragma unroll
    for (int mi = 0; mi < 4; ++mi)
      #pragma unroll
      for (int ni = 0; ni < 4; ++ni)
        acc[mi][ni] = MFMA16(af[mi], bf[ni], acc[mi][ni]);
  }

  #pragma unroll
  for (int mi = 0; mi < 4; ++mi) {
    long m = m0 + wr * 64 + mi * 16 + g * 4;
    int b = (int)(m >> 11);
    int t = (int)(m & 2047);
    #pragma unroll
    for (int ni = 0; ni < 4; ++ni) {
      int e = (int)n0 + wc * 64 + ni * 16 + l15;
      int sel = e >> 10;
      int ee = e & 1023;
      int h = ee >> 6, dh = ee & 63;
      size_t bh131k = (size_t)(b * 16 + h) * 131072u;
      if (sel < 2) {
        float sc = (sel == 0) ? QSCALE : 1.0f;
        size_t base = (size_t)sel * 8388608u + bh131k + (size_t)t * 64u + dh;
        #pragma unroll
        for (int r = 0; r < 4; ++r)
          outp[base + (size_t)r * 64u] = f2bf(acc[mi][ni][r] * sc);
      } else {
        size_t base = 16777216u + bh131k + (size_t)dh * 2048u + (size_t)t;
        us4 v;
        #pragma unroll
        for (int r = 0; r < 4; ++r) v[r] = f2bf(acc[mi][ni][r]);
        *(us4*)&outp[base] = v;
      }
    }
  }
}

// ---------------------------------------------------------------------------
// Output GEMM (128^2 structure): C = A_headed * w_out^T, f32 store.
// (VERBATIM — passed.)
// ---------------------------------------------------------------------------
__global__ __launch_bounds__(256)
void gemm_out(const u16* __restrict__ A, const u16* __restrict__ B,
              float* __restrict__ outf)
{
  __shared__ u16 Ash[128 * 32];
  __shared__ u16 Bsh[128 * 32];
  const int tid = threadIdx.x;
  const int lane = tid & 63;
  const int l15 = lane & 15, g = lane >> 4;
  const int w = tid >> 6;
  const int wr = w >> 1, wc = w & 1;

  const int bid = blockIdx.x;
  const int xcd = bid & 7, idx = bid >> 3;
  const int cx = xcd & 3, cy = xcd >> 2;
  const int mt = cx * 16 + (idx & 15);
  const int nt = cy * 4 + (idx >> 4);
  const long m0 = (long)mt * 128;
  const long n0 = (long)nt * 128;

  f32x4 acc[4][4] = {};

  const int c0 = tid, c1 = tid + 256;
  const long arow0 = m0 + (c0 >> 2), arow1 = m0 + (c1 >> 2);
  int b0 = (int)(arow0 >> 11), t0 = (int)(arow0 & 2047);
  int b1 = (int)(arow1 >> 11), t1 = (int)(arow1 & 2047);
  const u16* pa0 = A + (size_t)(b0 * 16) * 131072u + (size_t)t0 * 64u + (c0 & 3) * 8;
  const u16* pa1 = A + (size_t)(b1 * 16) * 131072u + (size_t)t1 * 64u + (c1 & 3) * 8;
  const u16* pb0 = B + (n0 + (c0 >> 2)) * 1024 + (c0 & 3) * 8;
  const u16* pb1 = B + (n0 + (c1 >> 2)) * 1024 + (c1 & 3) * 8;
  u16* la0 = Ash + c0 * 8;
  u16* la1 = Ash + c1 * 8;
  u16* lb0 = Bsh + c0 * 8;
  u16* lb1 = Bsh + c1 * 8;

  const u16* afp[4];
  const u16* bfp[4];
  #pragma unroll
  for (int mi = 0; mi < 4; ++mi)
    afp[mi] = &Ash[(wr * 64 + mi * 16 + l15) * 32 + g * 8];
  #pragma unroll
  for (int ni = 0; ni < 4; ++ni)
    bfp[ni] = &Bsh[(wc * 64 + ni * 16 + l15) * 32 + g * 8];

  for (int k0 = 0; k0 < 1024; k0 += 32) {
    __syncthreads();
    gl_lds16(pa0, la0); gl_lds16(pa1, la1);
    gl_lds16(pb0, lb0); gl_lds16(pb1, lb1);
    long d = (k0 & 32) ? (131072 - 32) : 32;
    pa0 += d; pa1 += d;
    pb0 += 32; pb1 += 32;
    __syncthreads();

    short8 af[4], bf[4];
    #pragma unroll
    for (int mi = 0; mi < 4; ++mi) af[mi] = *(const short8*)afp[mi];
    #pragma unroll
    for (int ni = 0; ni < 4; ++ni) bf[ni] = *(const short8*)bfp[ni];
    #pragma unroll
    for (int mi = 0; mi < 4; ++mi)
      #pragma unroll
      for (int ni = 0; ni < 4; ++ni)
        acc[mi][ni] = MFMA16(af[mi], bf[ni], acc[mi][ni]);
  }

  #pragma unroll
  for (int mi = 0; mi < 4; ++mi) {
    long m = m0 + wr * 64 + mi * 16 + g * 4;
    #pragma unroll
    for (int ni = 0; ni < 4; ++ni) {
      int n = (int)n0 + wc * 64 + ni * 16 + l15;
      #pragma unroll
      for (int r = 0; r < 4; ++r)
        outf[(m + r) * 1024 + n] = acc[mi][ni][r];
    }
  }
}

// ---------------------------------------------------------------------------
// Causal flash attention, swapped-QK^T form, SINGLE-SEGMENT.
// (VERBATIM from R14 — passed at 73.2us.)
// ---------------------------------------------------------------------------
__global__ __launch_bounds__(512, 4)
void attn(const u16* __restrict__ Q, const u16* __restrict__ K,
          const u16* __restrict__ VT, u16* __restrict__ O)
{
  __shared__ u16 Ksh[2][64 * 64];
  __shared__ u16 Vsh[2][64 * 64];
  __shared__ u16 Psh[8][16 * 64];

  const int tid = threadIdx.x;
  const int lane = tid & 63;
  const int l15 = lane & 15, g = lane >> 4;
  const int w = tid >> 6;
  const int bid = blockIdx.x;
  const int qi = (bid < 256) ? (7 - (bid >> 6)) : ((bid - 256) >> 6);
  const int bh = bid & 63;
  const int q0 = qi * 256;
  const int qb = q0 + w * 32;
  const int nt = qi * 4 + 4;

  const u16* Qp = Q + (size_t)bh * 131072u;
  const u16* Kp = K + (size_t)bh * 131072u;
  const u16* Vp = VT + (size_t)bh * 131072u;

  short8 qf[2][2];
  #pragma unroll
  for (int mi = 0; mi < 2; ++mi)
    #pragma unroll
    for (int kc = 0; kc < 2; ++kc)
      qf[mi][kc] = *(const short8*)&Qp[(qb + mi * 16 + l15) * 64 + kc * 32 + g * 8];

  f32x4 oacc[2][4] = {};
  float mrun[2] = {-1e30f, -1e30f};
  float lrun[2] = {0.f, 0.f};

  const int rA = tid >> 3, uA = ((tid & 7) ^ (rA & 7)) * 8;

#define STAGE(kv0s, b) do {                                            \
    gl_lds16(Kp + ((kv0s) + rA) * 64 + uA, Ksh[b] + tid * 8);          \
    gl_lds16(Vp + (size_t)rA * 2048u + (kv0s) + uA, Vsh[b] + tid * 8); \
  } while (0)

  STAGE(0, 0);
  int cur = 0;

  for (int ti = 0; ti < nt; ++ti) {
    const int kv0 = ti * 64;
    if (ti + 1 < nt) {
      STAGE(kv0 + 64, cur ^ 1);
      asm volatile("s_waitcnt vmcnt(2)" ::: "memory");
    } else {
      asm volatile("s_waitcnt vmcnt(0)" ::: "memory");
    }
    __builtin_amdgcn_s_barrier();
    __builtin_amdgcn_sched_barrier(0);

    if (kv0 <= qb + 31) {
      const u16* Kb = Ksh[cur];
      const u16* Vb = Vsh[cur];

      f32x4 s[2][4] = {};
      #pragma unroll
      for (int kc = 0; kc < 2; ++kc)
        #pragma unroll
        for (int ni = 0; ni < 4; ++ni) {
          int row = ni * 16 + l15;
          short8 kb = *(const short8*)&Kb[row * 64 + (((kc * 4 + g) ^ (row & 7)) << 3)];
          #pragma unroll
          for (int mi = 0; mi < 2; ++mi)
            s[mi][ni] = MFMA16(kb, qf[mi][kc], s[mi][ni]);
        }

      if (kv0 + 63 > qb) {
        #pragma unroll
        for (int mi = 0; mi < 2; ++mi) {
          int qv = qb + mi * 16 + l15;
          #pragma unroll
          for (int ni = 0; ni < 4; ++ni)
            #pragma unroll
            for (int r = 0; r < 4; ++r)
              if (kv0 + ni * 16 + g * 4 + r > qv)
                s[mi][ni][r] = -1e30f;
        }
      }

      #pragma unroll
      for (int mi = 0; mi < 2; ++mi) {
        // 16-value row max as max3 triples (5 max3 + 2 max3 + 1 max)
        float t0 = fmaxf(fmaxf(s[mi][0][0], s[mi][0][1]), s[mi][0][2]);
        float t1 = fmaxf(fmaxf(s[mi][0][3], s[mi][1][0]), s[mi][1][1]);
        float t2 = fmaxf(fmaxf(s[mi][1][2], s[mi][1][3]), s[mi][2][0]);
        float t3 = fmaxf(fmaxf(s[mi][2][1], s[mi][2][2]), s[mi][2][3]);
        float t4 = fmaxf(fmaxf(s[mi][3][0], s[mi][3][1]), s[mi][3][2]);
        float mx = fmaxf(fmaxf(fmaxf(t0, t1), t2),
                         fmaxf(fmaxf(t3, t4), s[mi][3][3]));
        mx = fmaxf(mx, __shfl_xor(mx, 16));
        mx = fmaxf(mx, __shfl_xor(mx, 32));
        if (!__all(mx - mrun[mi] <= 11.0f)) {      // exp2-domain defer-max
          float mn = fmaxf(mrun[mi], mx);
          float sc = fexp2(mrun[mi] - mn);
          mrun[mi] = mn;
          lrun[mi] *= sc;
          #pragma unroll
          for (int nj = 0; nj < 4; ++nj) {
            oacc[mi][nj][0] *= sc;
            oacc[mi][nj][1] *= sc;
            oacc[mi][nj][2] *= sc;
            oacc[mi][nj][3] *= sc;
          }
        }
        float mn = mrun[mi];
        float rs = 0.f;
        #pragma unroll
        for (int ni = 0; ni < 4; ++ni)
          #pragma unroll
          for (int r = 0; r < 4; ++r) {
            float pe = fexp2(s[mi][ni][r] - mn);   // bare v_exp_f32
            s[mi][ni][r] = pe;
            rs += pe;
          }
        rs += __shfl_xor(rs, 16);
        rs += __shfl_xor(rs, 32);
        lrun[mi] += rs;
      }

      u16* Pw = &Psh[w][0];
      short8 pb[2][2];
      #pragma unroll
      for (int mi = 0; mi < 2; ++mi) {
        #pragma unroll
        for (int ni = 0; ni < 4; ++ni) {
          int col = ni * 16 + g * 4;
          uint2 pv;
          pv.x = cvtpk(s[mi][ni][0], s[mi][ni][1]);
          pv.y = cvtpk(s[mi][ni][2], s[mi][ni][3]);
          *(uint2*)&Pw[l15 * 64 + (col ^ ((l15 & 7) << 3))] = pv;
        }
        #pragma unroll
        for (int kc = 0; kc < 2; ++kc)
          pb[mi][kc] = *(const short8*)&Pw[l15 * 64 + (((kc * 4 + g) ^ (l15 & 7)) << 3)];
      }

      #pragma unroll
      for (int kc = 0; kc < 2; ++kc)
        #pragma unroll
        for (int nj = 0; nj < 4; ++nj) {
          int vrow = nj * 16 + l15;
          short8 vb = *(const short8*)&Vb[vrow * 64 + (((kc * 4 + g) ^ (vrow & 7)) << 3)];
          #pragma unroll
          for (int mi = 0; mi < 2; ++mi)
            oacc[mi][nj] = MFMA16(vb, pb[mi][kc], oacc[mi][nj]);
        }
    }

    __builtin_amdgcn_sched_barrier(0);
    __builtin_amdgcn_s_barrier();
    cur ^= 1;
  }
#undef STAGE

  #pragma unroll
  for (int mi = 0; mi < 2; ++mi) {
    float inv = 1.0f / lrun[mi];
    int t = qb + mi * 16 + l15;
    size_t base = (size_t)bh * 131072u + (size_t)t * 64u;
    #pragma unroll
    for (int nj = 0; nj < 4; ++nj) {
      uint2 o;
      o.x = cvtpk(oacc[mi][nj][0] * inv, oacc[mi][nj][1] * inv);
      o.y = cvtpk(oacc[mi][nj][2] * inv, oacc[mi][nj][3] * inv);
      *(uint2*)&O[base + nj * 16 + g * 4] = o;
    }
  }
}

// ---------------------------------------------------------------------------
extern "C" void kernel_launch(void* const* d_in, const int* in_sizes, int n_in,
                              void* d_out, int out_size, void* d_ws, size_t ws_size,
                              hipStream_t stream)
{
  (void)in_sizes; (void)n_in; (void)out_size; (void)ws_size;
  const float* x    = (const float*)d_in[0];   // [8192][1024] f32
  const float* wqkv = (const float*)d_in[1];   // [3072][1024] f32
  const float* wout = (const float*)d_in[2];   // [1024][1024] f32
  u16* ws  = (u16*)d_ws;
  u16* Qw   = ws;                  // Q [bh][t][64]; later attn O (same layout)
  u16* Kw   = ws + 8388608;        // K [bh][t][64]
  u16* VTw  = ws + 16777216;       // VT [bh][dh][2048]
  u16* wqb  = ws + 25165824;       // w_qkv bf16 [3072][1024]
  u16* wob  = ws + 28311552;       // w_out bf16 [1024][1024]
  u16* xb   = (u16*)d_out;         // x bf16 [8192][1024] staged in d_out
  float* y  = (float*)d_out;       // final f32 output (overwrites xb)

  hipLaunchKernelGGL(cvt_bf16, dim3(2048), dim3(256), 0, stream, x,    xb,  1048576);
  hipLaunchKernelGGL(cvt_bf16, dim3(1536), dim3(256), 0, stream, wqkv, wqb, 393216);
  hipLaunchKernelGGL(cvt_bf16, dim3(512),  dim3(256), 0, stream, wout, wob, 131072);

  // 8-phase 256^2 needs 128KB dynamic LDS; opt in every call (idempotent,
  // deterministic, host-side only). Fall back to the proven 128^2 if denied.
  hipError_t e = hipFuncSetAttribute((const void*)gemm8p_qkv,
                   hipFuncAttributeMaxDynamicSharedMemorySize, 131072);
  if (e == hipSuccess) {
    hipLaunchKernelGGL(gemm8p_qkv, dim3(384), dim3(512), 131072, stream, xb, wqb, ws);
  } else {
    hipLaunchKernelGGL(gemm_qkv_fb, dim3(1536), dim3(256), 0, stream, xb, wqb, ws);
  }

  hipLaunchKernelGGL(attn,     dim3(512), dim3(512), 0, stream, Qw, Kw, VTw, Qw);
  hipLaunchKernelGGL(gemm_out, dim3(512), dim3(256), 0, stream, Qw, wob, y);
}

// Round 18
// 173.809 us; speedup vs baseline: 1.0465x; 1.0273x over previous
//
#include <hip/hip_runtime.h>

typedef __attribute__((ext_vector_type(8))) short short8;
typedef __attribute__((ext_vector_type(4))) float f32x4;
typedef __attribute__((ext_vector_type(4))) unsigned short us4;
typedef unsigned short u16;

#define MFMA16(a, b, c) __builtin_amdgcn_mfma_f32_16x16x32_bf16(a, b, c, 0, 0, 0)

// Q pre-scale: (1/sqrt(64)) * log2(e) — attention softmax runs in exp2 domain.
#define QSCALE 0.18033688011112042f

static __device__ __forceinline__ u16 f2bf(float f) {
  union { float f; unsigned u; } v; v.f = f;
  unsigned r = v.u + 0x7fffu + ((v.u >> 16) & 1u);
  return (u16)(r >> 16);
}

static __device__ __forceinline__ unsigned cvtpk(float lo, float hi) {
  unsigned r;
  asm("v_cvt_pk_bf16_f32 %0, %1, %2" : "=v"(r) : "v"(lo), "v"(hi));
  return r;
}

// Raw HW exp2: single v_exp_f32 (exp2f libm = multi-op OCML; __expf = mul+exp).
static __device__ __forceinline__ float fexp2(float x) {
#if __has_builtin(__builtin_amdgcn_exp2f)
  return __builtin_amdgcn_exp2f(x);
#else
  float r; asm("v_exp_f32 %0, %1" : "=v"(r) : "v"(x)); return r;
#endif
}

static __device__ __forceinline__ void gl_lds16(const u16* g, u16* l) {
  __builtin_amdgcn_global_load_lds((const __attribute__((address_space(1))) void*)g,
                                   (__attribute__((address_space(3))) void*)l,
                                   16, 0, 0);
}

#define BAR() do { __builtin_amdgcn_sched_barrier(0); \
                   __builtin_amdgcn_s_barrier();      \
                   __builtin_amdgcn_sched_barrier(0); } while (0)
#define LGK() do { asm volatile("s_waitcnt lgkmcnt(0)" ::: "memory"); \
                   __builtin_amdgcn_sched_barrier(0); } while (0)

// ---------------------------------------------------------------------------
// Fused f32 -> bf16 convert for all three inputs, 8 elems/unit, grid-stride.
// Ranges: x [0,1048576), wqkv [1048576,1441792), wout [1441792,1572864).
// Branch is wave-uniform except at the two range boundaries.
// ---------------------------------------------------------------------------
__global__ __launch_bounds__(256)
void cvt_all(const float* __restrict__ x, const float* __restrict__ wqkv,
             const float* __restrict__ wout, u16* __restrict__ xb,
             u16* __restrict__ wqb, u16* __restrict__ wob)
{
  int i = blockIdx.x * 256 + threadIdx.x;
  const int stride = gridDim.x * 256;
  for (; i < 1572864; i += stride) {
    const float* src; u16* dst; int j;
    if (i < 1048576)      { src = x;    dst = xb;  j = i; }
    else if (i < 1441792) { src = wqkv; dst = wqb; j = i - 1048576; }
    else                  { src = wout; dst = wob; j = i - 1441792; }
    f32x4 a = ((const f32x4*)src)[2 * j];
    f32x4 b = ((const f32x4*)src)[2 * j + 1];
    short8 o;
    o[0] = (short)f2bf(a[0]); o[1] = (short)f2bf(a[1]);
    o[2] = (short)f2bf(a[2]); o[3] = (short)f2bf(a[3]);
    o[4] = (short)f2bf(b[0]); o[5] = (short)f2bf(b[1]);
    o[6] = (short)f2bf(b[2]); o[7] = (short)f2bf(b[3]);
    ((short8*)dst)[j] = o;
  }
}

// ---------------------------------------------------------------------------
// Shared QKV epilogue: scatter acc[8][4] (wave tile 128x64 of a 256x256 C
// tile) into Q [bh][t][64] (x QSCALE), K [bh][t][64], VT [bh][dh][2048].
// ---------------------------------------------------------------------------
static __device__ __forceinline__ void qkv_scatter(
    f32x4 (*acc)[4], u16* __restrict__ outp,
    long m0, long n0, int wr, int wc, int l15, int g)
{
  #pragma unroll
  for (int mi = 0; mi < 8; ++mi) {
    long m = m0 + wr * 128 + mi * 16 + g * 4;   // rows m..m+3
    int b = (int)(m >> 11);
    int t = (int)(m & 2047);
    #pragma unroll
    for (int nj = 0; nj < 4; ++nj) {
      int e = (int)n0 + wc * 64 + nj * 16 + l15;   // 0..3071
      int sel = e >> 10;                            // 0=Q 1=K 2=V
      int ee = e & 1023;
      int h = ee >> 6, dh = ee & 63;
      size_t bh131k = (size_t)(b * 16 + h) * 131072u;
      if (sel < 2) {
        float sc = (sel == 0) ? QSCALE : 1.0f;     // fold 1/sqrt(64)*log2e in Q
        size_t base = (size_t)sel * 8388608u + bh131k + (size_t)t * 64u + dh;
        #pragma unroll
        for (int r = 0; r < 4; ++r)
          outp[base + (size_t)r * 64u] = f2bf(acc[mi][nj][r] * sc);
      } else {
        size_t base = 16777216u + bh131k + (size_t)dh * 2048u + (size_t)t;
        us4 v;
        #pragma unroll
        for (int r = 0; r < 4; ++r) v[r] = f2bf(acc[mi][nj][r]);
        *(us4*)&outp[base] = v;
      }
    }
  }
}

// ---------------------------------------------------------------------------
// QKV GEMM, m201-style 8-phase: 256x256 tile, BK=64, 8 waves (2M x 4N),
// 128KB dynamic LDS (2 bufs x (A 32KB + B 32KB)), 1 block/CU.
// (VERBATIM from R14/R17 — session-best gemm1 at 73.5us.)
// ---------------------------------------------------------------------------
__global__ __launch_bounds__(512, 2)
void gemm8p_qkv(const u16* __restrict__ A, const u16* __restrict__ B,
                u16* __restrict__ outp)
{
  extern __shared__ u16 lds[];   // 131072 B = 65536 elems

  const int tid = threadIdx.x;   // 0..511
  const int lane = tid & 63;
  const int l15 = lane & 15, g = lane >> 4;
  const int w = tid >> 6;
  const int wr = w >> 2, wc = w & 3;

  // XCD-chunked decode: 384 blocks = 8 XCD x (8 m-tiles x 6 n-tiles)
  const int bid = blockIdx.x;
  const int xcd = bid & 7, idx = bid >> 3;
  const int cx = xcd & 3, cy = xcd >> 2;
  const int mt = cx * 8 + (idx & 7);      // 0..31
  const int nt = cy * 6 + (idx >> 3);     // 0..11
  const long m0 = (long)mt * 256;
  const long n0 = (long)nt * 256;

  f32x4 acc[8][4] = {};

  // staging chunks: c0 = tid, c1 = tid+512 within each 1024-chunk plane
  const int c0 = tid, c1 = tid + 512;
  const int ar0 = c0 >> 2, ap0 = (c0 & 3) ^ ((ar0 >> 1) & 3);
  const int ar1 = c1 >> 2, ap1 = (c1 & 3) ^ ((ar1 >> 1) & 3);
  const u16* sA0 = A + (m0 + ar0) * 1024 + ap0 * 8;
  const u16* sA1 = A + (m0 + ar1) * 1024 + ap1 * 8;
  const u16* sB0 = B + (n0 + ar0) * 1024 + ap0 * 8;
  const u16* sB1 = B + (n0 + ar1) * 1024 + ap1 * 8;

  // frag offsets (elems) within a buffer, kk=0; kk=1 adds 8192.
  // buf layout: A kh0 @0, A kh1 @8192, B kh0 @16384, B kh1 @24576.
  int aoff[8], boff[4];
  #pragma unroll
  for (int mi = 0; mi < 8; ++mi) {
    int r = wr * 128 + mi * 16 + l15;
    aoff[mi] = r * 32 + (g ^ ((r >> 1) & 3)) * 8;
  }
  #pragma unroll
  for (int nj = 0; nj < 4; ++nj) {
    int r = wc * 64 + nj * 16 + l15;
    boff[nj] = 16384 + r * 32 + (g ^ ((r >> 1) & 3)) * 8;
  }

#define ST_A(kt, b, kh) do { \
    gl_lds16(sA0 + (kt) * 64 + (kh) * 32, &lds[(b) * 32768 + (kh) * 8192 + c0 * 8]); \
    gl_lds16(sA1 + (kt) * 64 + (kh) * 32, &lds[(b) * 32768 + (kh) * 8192 + c1 * 8]); \
  } while (0)
#define ST_B(kt, b, kh) do { \
    gl_lds16(sB0 + (kt) * 64 + (kh) * 32, &lds[(b) * 32768 + 16384 + (kh) * 8192 + c0 * 8]); \
    gl_lds16(sB1 + (kt) * 64 + (kh) * 32, &lds[(b) * 32768 + 16384 + (kh) * 8192 + c1 * 8]); \
  } while (0)

  // prologue: full tile 0, order A-Kh0, B-Kh0, A-Kh1, B-Kh1 (8 loads)
  ST_A(0, 0, 0); ST_B(0, 0, 0); ST_A(0, 0, 1); ST_B(0, 0, 1);

  for (int kt = 0; kt < 16; ++kt) {
    const int b = kt & 1, nb = b ^ 1;
    const bool more = (kt < 15);
    const u16* L = lds + b * 32768;
    short8 bf[4], af[4];

    // ---- P0: stage A-Kh0(T+1) | vmcnt | bar | read B.kk0 + A[0-3].kk0 ----
    if (more) { ST_A(kt + 1, nb, 0);
                asm volatile("s_waitcnt vmcnt(6)" ::: "memory"); }
    else      { asm volatile("s_waitcnt vmcnt(4)" ::: "memory"); }
    BAR();
    #pragma unroll
    for (int nj = 0; nj < 4; ++nj) bf[nj] = *(const short8*)&L[boff[nj]];
    #pragma unroll
    for (int mi = 0; mi < 4; ++mi) af[mi] = *(const short8*)&L[aoff[mi]];
    LGK();
    __builtin_amdgcn_s_setprio(1);
    #pragma unroll
    for (int mi = 0; mi < 4; ++mi)
      #pragma unroll
      for (int nj = 0; nj < 4; ++nj)
        acc[mi][nj] = MFMA16(af[mi], bf[nj], acc[mi][nj]);
    __builtin_amdgcn_s_setprio(0);

    // ---- P1: stage B-Kh0(T+1) | bar | read A[4-7].kk0 ----
    if (more) ST_B(kt + 1, nb, 0);
    BAR();
    #pragma unroll
    for (int mi = 0; mi < 4; ++mi) af[mi] = *(const short8*)&L[aoff[mi + 4]];
    LGK();
    __builtin_amdgcn_s_setprio(1);
    #pragma unroll
    for (int mi = 0; mi < 4; ++mi)
      #pragma unroll
      for (int nj = 0; nj < 4; ++nj)
        acc[mi + 4][nj] = MFMA16(af[mi], bf[nj], acc[mi + 4][nj]);
    __builtin_amdgcn_s_setprio(0);

    // ---- P2: stage A-Kh1(T+1) | vmcnt | bar | read B.kk1 + A[0-3].kk1 ----
    if (more) { ST_A(kt + 1, nb, 1);
                asm volatile("s_waitcnt vmcnt(6)" ::: "memory"); }
    else      { asm volatile("s_waitcnt vmcnt(0)" ::: "memory"); }
    BAR();
    #pragma unroll
    for (int nj = 0; nj < 4; ++nj) bf[nj] = *(const short8*)&L[boff[nj] + 8192];
    #pragma unroll
    for (int mi = 0; mi < 4; ++mi) af[mi] = *(const short8*)&L[aoff[mi] + 8192];
    LGK();
    __builtin_amdgcn_s_setprio(1);
    #pragma unroll
    for (int mi = 0; mi < 4; ++mi)
      #pragma unroll
      for (int nj = 0; nj < 4; ++nj)
        acc[mi][nj] = MFMA16(af[mi], bf[nj], acc[mi][nj]);
    __builtin_amdgcn_s_setprio(0);

    // ---- P3: stage B-Kh1(T+1) | bar | read A[4-7].kk1 ----
    if (more) ST_B(kt + 1, nb, 1);
    BAR();
    #pragma unroll
    for (int mi = 0; mi < 4; ++mi) af[mi] = *(const short8*)&L[aoff[mi + 4] + 8192];
    LGK();
    __builtin_amdgcn_s_setprio(1);
    #pragma unroll
    for (int mi = 0; mi < 4; ++mi)
      #pragma unroll
      for (int nj = 0; nj < 4; ++nj)
        acc[mi + 4][nj] = MFMA16(af[mi], bf[nj], acc[mi + 4][nj]);
    __builtin_amdgcn_s_setprio(0);

    BAR();   // trailing: all reads of buf[b] done -> T+1 may overwrite it
  }
#undef ST_A
#undef ST_B

  qkv_scatter(acc, outp, m0, n0, wr, wc, l15, g);
}

// ---------------------------------------------------------------------------
// Fallback QKV GEMM (proven 128^2 structure) — used only if the
// dynamic-LDS attribute call fails.
// ---------------------------------------------------------------------------
__global__ __launch_bounds__(256)
void gemm_qkv_fb(const u16* __restrict__ A, const u16* __restrict__ B,
                 u16* __restrict__ outp)
{
  __shared__ u16 Ash[128 * 32];
  __shared__ u16 Bsh[128 * 32];
  const int tid = threadIdx.x;
  const int lane = tid & 63;
  const int l15 = lane & 15, g = lane >> 4;
  const int w = tid >> 6;
  const int wr = w >> 1, wc = w & 1;

  const int bid = blockIdx.x;
  const int xcd = bid & 7, idx = bid >> 3;
  const int cx = xcd & 3, cy = xcd >> 2;
  const int mt = cx * 16 + (idx & 15);
  const int nt = cy * 12 + (idx >> 4);
  const long m0 = (long)mt * 128;
  const long n0 = (long)nt * 128;

  f32x4 acc[4][4] = {};

  const int c0 = tid, c1 = tid + 256;
  const u16* pa0 = A + (m0 + (c0 >> 2)) * 1024 + (c0 & 3) * 8;
  const u16* pa1 = A + (m0 + (c1 >> 2)) * 1024 + (c1 & 3) * 8;
  const u16* pb0 = B + (n0 + (c0 >> 2)) * 1024 + (c0 & 3) * 8;
  const u16* pb1 = B + (n0 + (c1 >> 2)) * 1024 + (c1 & 3) * 8;
  u16* la0 = Ash + c0 * 8;
  u16* la1 = Ash + c1 * 8;
  u16* lb0 = Bsh + c0 * 8;
  u16* lb1 = Bsh + c1 * 8;

  const u16* afp[4];
  const u16* bfp[4];
  #pragma unroll
  for (int mi = 0; mi < 4; ++mi)
    afp[mi] = &Ash[(wr * 64 + mi * 16 + l15) * 32 + g * 8];
  #pragma unroll
  for (int ni = 0; ni < 4; ++ni)
    bfp[ni] = &Bsh[(wc * 64 + ni * 16 + l15) * 32 + g * 8];

  for (int k0 = 0; k0 < 1024; k0 += 32) {
    __syncthreads();
    gl_lds16(pa0, la0); gl_lds16(pa1, la1);
    gl_lds16(pb0, lb0); gl_lds16(pb1, lb1);
    pa0 += 32; pa1 += 32; pb0 += 32; pb1 += 32;
    __syncthreads();
    short8 af[4], bf[4];
    #pragma unroll
    for (int mi = 0; mi < 4; ++mi) af[mi] = *(const short8*)afp[mi];
    #pragma unroll
    for (int ni = 0; ni < 4; ++ni) bf[ni] = *(const short8*)bfp[ni];
    #pragma unroll
    for (int mi = 0; mi < 4; ++mi)
      #pragma unroll
      for (int ni = 0; ni < 4; ++ni)
        acc[mi][ni] = MFMA16(af[mi], bf[ni], acc[mi][ni]);
  }

  #pragma unroll
  for (int mi = 0; mi < 4; ++mi) {
    long m = m0 + wr * 64 + mi * 16 + g * 4;
    int b = (int)(m >> 11);
    int t = (int)(m & 2047);
    #pragma unroll
    for (int ni = 0; ni < 4; ++ni) {
      int e = (int)n0 + wc * 64 + ni * 16 + l15;
      int sel = e >> 10;
      int ee = e & 1023;
      int h = ee >> 6, dh = ee & 63;
      size_t bh131k = (size_t)(b * 16 + h) * 131072u;
      if (sel < 2) {
        float sc = (sel == 0) ? QSCALE : 1.0f;
        size_t base = (size_t)sel * 8388608u + bh131k + (size_t)t * 64u + dh;
        #pragma unroll
        for (int r = 0; r < 4; ++r)
          outp[base + (size_t)r * 64u] = f2bf(acc[mi][ni][r] * sc);
      } else {
        size_t base = 16777216u + bh131k + (size_t)dh * 2048u + (size_t)t;
        us4 v;
        #pragma unroll
        for (int r = 0; r < 4; ++r) v[r] = f2bf(acc[mi][ni][r]);
        *(us4*)&outp[base] = v;
      }
    }
  }
}

// ---------------------------------------------------------------------------
// Output GEMM (128^2 structure): C = A_headed * w_out^T, f32 store.
// (VERBATIM — passed.)
// ---------------------------------------------------------------------------
__global__ __launch_bounds__(256)
void gemm_out(const u16* __restrict__ A, const u16* __restrict__ B,
              float* __restrict__ outf)
{
  __shared__ u16 Ash[128 * 32];
  __shared__ u16 Bsh[128 * 32];
  const int tid = threadIdx.x;
  const int lane = tid & 63;
  const int l15 = lane & 15, g = lane >> 4;
  const int w = tid >> 6;
  const int wr = w >> 1, wc = w & 1;

  const int bid = blockIdx.x;
  const int xcd = bid & 7, idx = bid >> 3;
  const int cx = xcd & 3, cy = xcd >> 2;
  const int mt = cx * 16 + (idx & 15);
  const int nt = cy * 4 + (idx >> 4);
  const long m0 = (long)mt * 128;
  const long n0 = (long)nt * 128;

  f32x4 acc[4][4] = {};

  const int c0 = tid, c1 = tid + 256;
  const long arow0 = m0 + (c0 >> 2), arow1 = m0 + (c1 >> 2);
  int b0 = (int)(arow0 >> 11), t0 = (int)(arow0 & 2047);
  int b1 = (int)(arow1 >> 11), t1 = (int)(arow1 & 2047);
  const u16* pa0 = A + (size_t)(b0 * 16) * 131072u + (size_t)t0 * 64u + (c0 & 3) * 8;
  const u16* pa1 = A + (size_t)(b1 * 16) * 131072u + (size_t)t1 * 64u + (c1 & 3) * 8;
  const u16* pb0 = B + (n0 + (c0 >> 2)) * 1024 + (c0 & 3) * 8;
  const u16* pb1 = B + (n0 + (c1 >> 2)) * 1024 + (c1 & 3) * 8;
  u16* la0 = Ash + c0 * 8;
  u16* la1 = Ash + c1 * 8;
  u16* lb0 = Bsh + c0 * 8;
  u16* lb1 = Bsh + c1 * 8;

  const u16* afp[4];
  const u16* bfp[4];
  #pragma unroll
  for (int mi = 0; mi < 4; ++mi)
    afp[mi] = &Ash[(wr * 64 + mi * 16 + l15) * 32 + g * 8];
  #pragma unroll
  for (int ni = 0; ni < 4; ++ni)
    bfp[ni] = &Bsh[(wc * 64 + ni * 16 + l15) * 32 + g * 8];

  for (int k0 = 0; k0 < 1024; k0 += 32) {
    __syncthreads();
    gl_lds16(pa0, la0); gl_lds16(pa1, la1);
    gl_lds16(pb0, lb0); gl_lds16(pb1, lb1);
    long d = (k0 & 32) ? (131072 - 32) : 32;
    pa0 += d; pa1 += d;
    pb0 += 32; pb1 += 32;
    __syncthreads();

    short8 af[4], bf[4];
    #pragma unroll
    for (int mi = 0; mi < 4; ++mi) af[mi] = *(const short8*)afp[mi];
    #pragma unroll
    for (int ni = 0; ni < 4; ++ni) bf[ni] = *(const short8*)bfp[ni];
    #pragma unroll
    for (int mi = 0; mi < 4; ++mi)
      #pragma unroll
      for (int ni = 0; ni < 4; ++ni)
        acc[mi][ni] = MFMA16(af[mi], bf[ni], acc[mi][ni]);
  }

  #pragma unroll
  for (int mi = 0; mi < 4; ++mi) {
    long m = m0 + wr * 64 + mi * 16 + g * 4;
    #pragma unroll
    for (int ni = 0; ni < 4; ++ni) {
      int n = (int)n0 + wc * 64 + ni * 16 + l15;
      #pragma unroll
      for (int r = 0; r < 4; ++r)
        outf[(m + r) * 1024 + n] = acc[mi][ni][r];
    }
  }
}

// ---------------------------------------------------------------------------
// Causal flash attention, swapped-QK^T form, SINGLE-SEGMENT.
// (VERBATIM from R14/R17 — passed at 73.2us.)
// ---------------------------------------------------------------------------
__global__ __launch_bounds__(512, 4)
void attn(const u16* __restrict__ Q, const u16* __restrict__ K,
          const u16* __restrict__ VT, u16* __restrict__ O)
{
  __shared__ u16 Ksh[2][64 * 64];
  __shared__ u16 Vsh[2][64 * 64];
  __shared__ u16 Psh[8][16 * 64];

  const int tid = threadIdx.x;
  const int lane = tid & 63;
  const int l15 = lane & 15, g = lane >> 4;
  const int w = tid >> 6;
  const int bid = blockIdx.x;
  const int qi = (bid < 256) ? (7 - (bid >> 6)) : ((bid - 256) >> 6);
  const int bh = bid & 63;
  const int q0 = qi * 256;
  const int qb = q0 + w * 32;
  const int nt = qi * 4 + 4;

  const u16* Qp = Q + (size_t)bh * 131072u;
  const u16* Kp = K + (size_t)bh * 131072u;
  const u16* Vp = VT + (size_t)bh * 131072u;

  short8 qf[2][2];
  #pragma unroll
  for (int mi = 0; mi < 2; ++mi)
    #pragma unroll
    for (int kc = 0; kc < 2; ++kc)
      qf[mi][kc] = *(const short8*)&Qp[(qb + mi * 16 + l15) * 64 + kc * 32 + g * 8];

  f32x4 oacc[2][4] = {};
  float mrun[2] = {-1e30f, -1e30f};
  float lrun[2] = {0.f, 0.f};

  const int rA = tid >> 3, uA = ((tid & 7) ^ (rA & 7)) * 8;

#define STAGE(kv0s, b) do {                                            \
    gl_lds16(Kp + ((kv0s) + rA) * 64 + uA, Ksh[b] + tid * 8);          \
    gl_lds16(Vp + (size_t)rA * 2048u + (kv0s) + uA, Vsh[b] + tid * 8); \
  } while (0)

  STAGE(0, 0);
  int cur = 0;

  for (int ti = 0; ti < nt; ++ti) {
    const int kv0 = ti * 64;
    if (ti + 1 < nt) {
      STAGE(kv0 + 64, cur ^ 1);
      asm volatile("s_waitcnt vmcnt(2)" ::: "memory");
    } else {
      asm volatile("s_waitcnt vmcnt(0)" ::: "memory");
    }
    __builtin_amdgcn_s_barrier();
    __builtin_amdgcn_sched_barrier(0);

    if (kv0 <= qb + 31) {
      const u16* Kb = Ksh[cur];
      const u16* Vb = Vsh[cur];

      f32x4 s[2][4] = {};
      #pragma unroll
      for (int kc = 0; kc < 2; ++kc)
        #pragma unroll
        for (int ni = 0; ni < 4; ++ni) {
          int row = ni * 16 + l15;
          short8 kb = *(const short8*)&Kb[row * 64 + (((kc * 4 + g) ^ (row & 7)) << 3)];
          #pragma unroll
          for (int mi = 0; mi < 2; ++mi)
            s[mi][ni] = MFMA16(kb, qf[mi][kc], s[mi][ni]);
        }

      if (kv0 + 63 > qb) {
        #pragma unroll
        for (int mi = 0; mi < 2; ++mi) {
          int qv = qb + mi * 16 + l15;
          #pragma unroll
          for (int ni = 0; ni < 4; ++ni)
            #pragma unroll
            for (int r = 0; r < 4; ++r)
              if (kv0 + ni * 16 + g * 4 + r > qv)
                s[mi][ni][r] = -1e30f;
        }
      }

      #pragma unroll
      for (int mi = 0; mi < 2; ++mi) {
        // 16-value row max as max3 triples (5 max3 + 2 max3 + 1 max)
        float t0 = fmaxf(fmaxf(s[mi][0][0], s[mi][0][1]), s[mi][0][2]);
        float t1 = fmaxf(fmaxf(s[mi][0][3], s[mi][1][0]), s[mi][1][1]);
        float t2 = fmaxf(fmaxf(s[mi][1][2], s[mi][1][3]), s[mi][2][0]);
        float t3 = fmaxf(fmaxf(s[mi][2][1], s[mi][2][2]), s[mi][2][3]);
        float t4 = fmaxf(fmaxf(s[mi][3][0], s[mi][3][1]), s[mi][3][2]);
        float mx = fmaxf(fmaxf(fmaxf(t0, t1), t2),
                         fmaxf(fmaxf(t3, t4), s[mi][3][3]));
        mx = fmaxf(mx, __shfl_xor(mx, 16));
        mx = fmaxf(mx, __shfl_xor(mx, 32));
        if (!__all(mx - mrun[mi] <= 11.0f)) {      // exp2-domain defer-max
          float mn = fmaxf(mrun[mi], mx);
          float sc = fexp2(mrun[mi] - mn);
          mrun[mi] = mn;
          lrun[mi] *= sc;
          #pragma unroll
          for (int nj = 0; nj < 4; ++nj) {
            oacc[mi][nj][0] *= sc;
            oacc[mi][nj][1] *= sc;
            oacc[mi][nj][2] *= sc;
            oacc[mi][nj][3] *= sc;
          }
        }
        float mn = mrun[mi];
        float rs = 0.f;
        #pragma unroll
        for (int ni = 0; ni < 4; ++ni)
          #pragma unroll
          for (int r = 0; r < 4; ++r) {
            float pe = fexp2(s[mi][ni][r] - mn);   // bare v_exp_f32
            s[mi][ni][r] = pe;
            rs += pe;
          }
        rs += __shfl_xor(rs, 16);
        rs += __shfl_xor(rs, 32);
        lrun[mi] += rs;
      }

      u16* Pw = &Psh[w][0];
      short8 pb[2][2];
      #pragma unroll
      for (int mi = 0; mi < 2; ++mi) {
        #pragma unroll
        for (int ni = 0; ni < 4; ++ni) {
          int col = ni * 16 + g * 4;
          uint2 pv;
          pv.x = cvtpk(s[mi][ni][0], s[mi][ni][1]);
          pv.y = cvtpk(s[mi][ni][2], s[mi][ni][3]);
          *(uint2*)&Pw[l15 * 64 + (col ^ ((l15 & 7) << 3))] = pv;
        }
        #pragma unroll
        for (int kc = 0; kc < 2; ++kc)
          pb[mi][kc] = *(const short8*)&Pw[l15 * 64 + (((kc * 4 + g) ^ (l15 & 7)) << 3)];
      }

      #pragma unroll
      for (int kc = 0; kc < 2; ++kc)
        #pragma unroll
        for (int nj = 0; nj < 4; ++nj) {
          int vrow = nj * 16 + l15;
          short8 vb = *(const short8*)&Vb[vrow * 64 + (((kc * 4 + g) ^ (vrow & 7)) << 3)];
          #pragma unroll
          for (int mi = 0; mi < 2; ++mi)
            oacc[mi][nj] = MFMA16(vb, pb[mi][kc], oacc[mi][nj]);
        }
    }

    __builtin_amdgcn_sched_barrier(0);
    __builtin_amdgcn_s_barrier();
    cur ^= 1;
  }
#undef STAGE

  #pragma unroll
  for (int mi = 0; mi < 2; ++mi) {
    float inv = 1.0f / lrun[mi];
    int t = qb + mi * 16 + l15;
    size_t base = (size_t)bh * 131072u + (size_t)t * 64u;
    #pragma unroll
    for (int nj = 0; nj < 4; ++nj) {
      uint2 o;
      o.x = cvtpk(oacc[mi][nj][0] * inv, oacc[mi][nj][1] * inv);
      o.y = cvtpk(oacc[mi][nj][2] * inv, oacc[mi][nj][3] * inv);
      *(uint2*)&O[base + nj * 16 + g * 4] = o;
    }
  }
}

// ---------------------------------------------------------------------------
extern "C" void kernel_launch(void* const* d_in, const int* in_sizes, int n_in,
                              void* d_out, int out_size, void* d_ws, size_t ws_size,
                              hipStream_t stream)
{
  (void)in_sizes; (void)n_in; (void)out_size; (void)ws_size;
  const float* x    = (const float*)d_in[0];   // [8192][1024] f32
  const float* wqkv = (const float*)d_in[1];   // [3072][1024] f32
  const float* wout = (const float*)d_in[2];   // [1024][1024] f32
  u16* ws  = (u16*)d_ws;
  u16* Qw   = ws;                  // Q [bh][t][64]; later attn O (same layout)
  u16* Kw   = ws + 8388608;        // K [bh][t][64]
  u16* VTw  = ws + 16777216;       // VT [bh][dh][2048]
  u16* wqb  = ws + 25165824;       // w_qkv bf16 [3072][1024]
  u16* wob  = ws + 28311552;       // w_out bf16 [1024][1024]
  u16* xb   = (u16*)d_out;         // x bf16 [8192][1024] staged in d_out
  float* y  = (float*)d_out;       // final f32 output (overwrites xb)

  hipLaunchKernelGGL(cvt_all, dim3(2048), dim3(256), 0, stream,
                     x, wqkv, wout, xb, wqb, wob);

  // 8-phase 256^2 needs 128KB dynamic LDS; opt in every call (idempotent,
  // deterministic, host-side only). Fall back to the proven 128^2 if denied.
  hipError_t e = hipFuncSetAttribute((const void*)gemm8p_qkv,
                   hipFuncAttributeMaxDynamicSharedMemorySize, 131072);
  if (e == hipSuccess) {
    hipLaunchKernelGGL(gemm8p_qkv, dim3(384), dim3(512), 131072, stream, xb, wqb, ws);
  } else {
    hipLaunchKernelGGL(gemm_qkv_fb, dim3(1536), dim3(256), 0, stream, xb, wqb, ws);
  }

  hipLaunchKernelGGL(attn,     dim3(512), dim3(512), 0, stream, Qw, Kw, VTw, Qw);
  hipLaunchKernelGGL(gemm_out, dim3(512), dim3(256), 0, stream, Qw, wob, y);
}